// Round 5
// baseline (117.808 us; speedup 1.0000x reference)
//
#include <hip/hip_runtime.h>

// Signature_72327249265296: depth-4 path signature, path [64,512,10] fp32.
// out[b] = concat(A1[10], A2[100], A3[1000], A4[10000]).
//
// V5: V4's 5-chains-per-thread math (passed), re-scheduled.
// V4 post-mortem: 1690 cy/CU-step with LDS+VALU both ~17% busy ->
// latency-bound; ~14 LDS ops x ~120cy serialized because ~100 live regs left
// no headroom for in-flight loads and 2 waves/SIMD gave no TLP. Fixes:
//   - NSEG 8 -> 16 (SEGLEN 32): 1024 blocks x 4 waves = 4096 waves =
//     16 waves/CU = 4 waves/SIMD. Total LDS work invariant (~7.7us).
//   - __launch_bounds__(256, 2): cap 128 VGPRs -> guarantees 4 waves/SIMD
//     occupancy (demand est. ~110).
//   - plain template<int H> device fn (wave-uniform branch, tid>>7).
// Per-thread: owns (i,j) x 5 k's. d-row (10 floats) read once per step
// serves the A4 broadcast AND all 5 dx_k. Shared Horner prefix on (i,j).
// Chen per-step recurrence per chain (i,j,k) (validated V1/V2/V4):
//   p1 = A1/6 + dxi/24 ; q1 = A1/2 + dxi/6 ; r1 = A1 + dxi/2
//   p2 = A2/2 + p1*dxj ; q2 = A2 + q1*dxj  ; A2 += r1*dxj
//   p3k = A3k + p2*dk  ; A3k += q2*dk      ; A1 += dxi
//   A4[k][l] += p3k*d[l]
// Segment combine (validated V2-V4): serial Chen fold of NSEG partials.
// Fill note: the ~45us 256MiB workspace poison is in the timed graph
// unconditionally (present in round 0 which used no ws) -> ws use is free.

#define CH      10
#define NSTEPS  511
#define SIGSZ   11110
#define WSSEG   11112                    // per-partial stride (16B-aligned)
#define NSEG    16
#define SEGLEN  32
#define TRP     36                       // transposed LDS stride (2-way alias only)

template<int H>
__device__ __forceinline__ void run_chains(
    const float* __restrict__ rowL, const float* __restrict__ ti,
    const float* __restrict__ tj, float& a1, float& a2,
    float* __restrict__ a3, float (* __restrict__ a4)[10])
{
    #pragma unroll 2
    for (int s4 = 0; s4 < SEGLEN; s4 += 4) {
        const float4 vi = *(const float4*)(ti + s4);
        const float4 vj = *(const float4*)(tj + s4);
        const float* rp = rowL + s4 * 12;
        #pragma unroll
        for (int u = 0; u < 4; ++u) {
            const float4 d0 = *(const float4*)(rp + u * 12);
            const float4 d1 = *(const float4*)(rp + u * 12 + 4);
            const float2 d2 = *(const float2*)(rp + u * 12 + 8);
            const float dxi = (u == 0) ? vi.x : (u == 1) ? vi.y
                             : (u == 2) ? vi.z : vi.w;
            const float dxj = (u == 0) ? vj.x : (u == 1) ? vj.y
                             : (u == 2) ? vj.z : vj.w;

            // shared (i,j) Horner prefix
            const float p1 = a1 * (1.f / 6.f) + dxi * (1.f / 24.f);
            const float q1 = a1 * 0.5f        + dxi * (1.f / 6.f);
            const float r1 = a1               + dxi * 0.5f;
            const float p2 = a2 * 0.5f + p1 * dxj;
            const float q2 = a2        + q1 * dxj;
            a2 += r1 * dxj;
            a1 += dxi;

            // this half's 5 k-values (compile-time selection, no indexing)
            const float dk0 = H ? d1.y : d0.x;
            const float dk1 = H ? d1.z : d0.y;
            const float dk2 = H ? d1.w : d0.z;
            const float dk3 = H ? d2.x : d0.w;
            const float dk4 = H ? d2.y : d1.x;

            const float p30 = a3[0] + p2 * dk0;  a3[0] += q2 * dk0;
            const float p31 = a3[1] + p2 * dk1;  a3[1] += q2 * dk1;
            const float p32 = a3[2] + p2 * dk2;  a3[2] += q2 * dk2;
            const float p33 = a3[3] + p2 * dk3;  a3[3] += q2 * dk3;
            const float p34 = a3[4] + p2 * dk4;  a3[4] += q2 * dk4;

            #pragma unroll
            for (int m = 0; m < 5; ++m) {
                const float p3 = (m == 0) ? p30 : (m == 1) ? p31
                                : (m == 2) ? p32 : (m == 3) ? p33 : p34;
                a4[m][0] += p3 * d0.x; a4[m][1] += p3 * d0.y;
                a4[m][2] += p3 * d0.z; a4[m][3] += p3 * d0.w;
                a4[m][4] += p3 * d1.x; a4[m][5] += p3 * d1.y;
                a4[m][6] += p3 * d1.z; a4[m][7] += p3 * d1.w;
                a4[m][8] += p3 * d2.x; a4[m][9] += p3 * d2.y;
            }
        }
    }
}

__global__ __launch_bounds__(256, 2)
void sig_partial(const float* __restrict__ path, float* __restrict__ ws) {
    __shared__ __align__(16) float rowL[SEGLEN * 12];   // [s][c] padded rows
    __shared__ __align__(16) float trL[CH * TRP];       // [c][s] transposed

    const int tid = threadIdx.x;
    const int bx  = blockIdx.x;          // 1024 = 64 batches x 16 segments
    const int b   = bx >> 4;
    const int seg = bx & 15;
    const int s0  = seg * SEGLEN;

    // ---- stage this segment's increments into both LDS layouts ----
    const float* p = path + (size_t)b * (512 * CH) + s0 * CH;
    for (int e = tid; e < SEGLEN * CH; e += 256) {
        const int s = e / CH;
        const int c = e - s * CH;
        float v = 0.f;
        if (s0 + s < NSTEPS) v = p[e + CH] - p[e];   // seg 15 step 31 = 0 pad
        rowL[s * 12 + c] = v;
        trL[c * TRP + s] = v;
    }
    __syncthreads();

    // thread -> (i,j, k-half): tid 0..99 -> half 0, tid 128..227 -> half 1.
    // half = tid>>7 is wave-uniform (waves 0,1 vs waves 2,3).
    const int half = tid >> 7;
    const int ij   = tid & 127;
    if (ij < 100) {
        const int ci = ij / 10;
        const int cj = ij - ci * 10;

        float a1 = 0.f, a2 = 0.f;
        float a3[5];
        float a4[5][10];
        #pragma unroll
        for (int m = 0; m < 5; ++m) {
            a3[m] = 0.f;
            #pragma unroll
            for (int l = 0; l < 10; ++l) a4[m][l] = 0.f;
        }

        const float* ti = trL + ci * TRP;
        const float* tj = trL + cj * TRP;

        if (half == 0) run_chains<0>(rowL, ti, tj, a1, a2, a3, a4);
        else           run_chains<1>(rowL, ti, tj, a1, a2, a3, a4);

        // ---- epilogue: write this thread's share of the segment partial ----
        const int k0 = half * 5;
        float* ob = ws + (size_t)(b * NSEG + seg) * WSSEG;
        #pragma unroll
        for (int m = 0; m < 5; ++m) {
            const int id = ci * 100 + cj * 10 + k0 + m;
            float* o4 = ob + 1110 + id * 10;
            #pragma unroll
            for (int l = 0; l < 10; ++l) o4[l] = a4[m][l];
            ob[110 + id] = a3[m];
        }
        if (half == 0)            ob[10 + ci * 10 + cj] = a2;
        if (half == 0 && cj == 0) ob[ci] = a1;
    }
}

__global__ __launch_bounds__(256)
void sig_combine(const float* __restrict__ ws, float* __restrict__ out) {
    __shared__ float B[1110];             // levels 1-3 of one segment partial

    const int tid  = threadIdx.x;
    const int b    = blockIdx.x >> 2;
    const int part = blockIdx.x & 3;
    const int id   = part * 256 + tid;
    const bool valid = (id < 1000);

    const int ci = id / 100;
    const int cj = (id / 10) % 10;
    const int ck = id % 10;

    const float* w0 = ws + (size_t)b * NSEG * WSSEG;

    float a1 = 0.f, a2 = 0.f, a3 = 0.f;
    float a4[10];
    #pragma unroll
    for (int l = 0; l < 10; ++l) a4[l] = 0.f;
    if (valid) {
        a1 = w0[ci];
        a2 = w0[10 + ci * 10 + cj];
        a3 = w0[110 + id];
        #pragma unroll
        for (int l = 0; l < 10; ++l) a4[l] = w0[1110 + id * 10 + l];
    }

    for (int s = 1; s < NSEG; ++s) {
        const float* wb = w0 + (size_t)s * WSSEG;
        __syncthreads();                  // previous iter done reading B
        for (int e = tid; e < 1110; e += 256) B[e] = wb[e];
        __syncthreads();

        if (valid) {
            const float b1i   = B[ci];
            const float b1j   = B[cj];
            const float b1k   = B[ck];
            const float b2_ij = B[10 + ci * 10 + cj];
            const float b2_jk = B[10 + cj * 10 + ck];
            const float b3ijk = B[110 + id];

            float b4v[10];
            #pragma unroll
            for (int l = 0; l < 10; ++l) b4v[l] = wb[1110 + id * 10 + l];

            // Z4 uses OLD a1,a2,a3 (computed before lower levels update)
            #pragma unroll
            for (int l = 0; l < 10; ++l)
                a4[l] += a3 * B[l] + a2 * B[10 + ck * 10 + l]
                       + a1 * B[110 + (cj * 10 + ck) * 10 + l] + b4v[l];
            a3 += a2 * b1k + a1 * b2_jk + b3ijk;
            a2 += a1 * b1j + b2_ij;
            a1 += b1i;
        }
    }

    if (valid) {
        float* ob = out + (size_t)b * SIGSZ;
        float* o4 = ob + 1110 + id * 10;
        #pragma unroll
        for (int l = 0; l < 10; ++l) o4[l] = a4[l];
        ob[110 + id] = a3;
        if (ck == 0)            ob[10 + ci * 10 + cj] = a2;
        if (ck == 0 && cj == 0) ob[ci] = a1;
    }
}

extern "C" void kernel_launch(void* const* d_in, const int* in_sizes, int n_in,
                              void* d_out, int out_size, void* d_ws, size_t ws_size,
                              hipStream_t stream) {
    const float* path = (const float*)d_in[0];   // [64, 512, 10] fp32
    float* out = (float*)d_out;                  // [64, 11110] fp32
    float* ws  = (float*)d_ws;                   // 64*16*11112 floats = 45.5 MB

    sig_partial<<<dim3(1024), dim3(256), 0, stream>>>(path, ws);
    sig_combine<<<dim3(256),  dim3(256), 0, stream>>>(ws, out);
}

// Round 7
// 100.282 us; speedup vs baseline: 1.1748x; 1.1748x over previous
//
#include <hip/hip_runtime.h>

// Signature_72327249265296: depth-4 path signature, path [64,512,10] fp32.
// out[b] = concat(A1[10], A2[100], A3[1000], A4[10000]).
//
// V6 (resubmit — round 6 failed on container acquisition, not the kernel):
// V2's proven 1-chain-per-thread loop (small state -> LDS loads pipeline),
// with the wave-uniform d-row broadcast moved OFF the LDS pipe:
//   - per 32 steps, the 320 row floats are loaded once as 5 conflict-free
//     ds_read_b32 (lane L holds flat[g*320 + r*64 + L]), then each d[c] is
//     extracted via v_readlane_b32 at compile-time (reg,lane) -> SGPR.
//     A4 FMAs read the SGPR directly (1 SGPR/VALU-instr is legal).
//     This converts ~28 LDS-cyc/step/wave (per-CU pipe shared by 4 SIMDs)
//     into ~20 VALU-cyc/step (per-SIMD) + 1.6 LDS-cyc.
//   - per-lane dxi/dxj/dxk from transposed trL as float4-per-4-steps.
//   - V4/V5 lesson: ~110-reg variants serialize ds_read latency (no regalloc
//     headroom); this kernel stays ~50 VGPR so loads stay in flight.
//   - ALL lanes run the loop (readlane needs every lane's f-regs valid even
//     in the tail wave ids 960..1023); only epilogue writes are guarded.
// Chen per-step recurrence per chain (validated V1/V2/V4/V5):
//   p1 = A1/6 + dxi/24 ; q1 = A1/2 + dxi/6 ; r1 = A1 + dxi/2
//   p2 = A2/2 + p1*dxj ; q2 = A2 + q1*dxj  ; A2 += r1*dxj
//   p3 = A3 + p2*dxk   ; A3 += q2*dxk      ; A1 += dxi ; A4[l] += p3*d[l]
// Segment combine (validated V2-V5): serial Chen fold of NSEG=4 partials.
// The ~45us 256MiB workspace poison is in the timed graph unconditionally.

#define CH      10
#define NSTEPS  511
#define SIGSZ   11110
#define WSSEG   11112                    // per-partial stride (16B-aligned)
#define NSEG    4
#define SEGLEN  128
#define TRP     132                      // transposed stride: 16B-aligned, banks ok
#define GSTEPS  32                       // steps per readlane group (320 = 5 regs)
#define NGRP    (SEGLEN / GSTEPS)

__device__ __forceinline__ float rl(float v, int lane) {
    return __int_as_float(__builtin_amdgcn_readlane(__float_as_int(v), lane));
}

__global__ __launch_bounds__(256)
void sig_partial(const float* __restrict__ path, float* __restrict__ ws) {
    __shared__ __align__(16) float flatL[SEGLEN * CH];   // [s][c] packed rows
    __shared__ __align__(16) float trL[CH * TRP];        // [c][s] transposed

    const int tid  = threadIdx.x;
    const int lane = tid & 63;
    const int bx   = blockIdx.x;          // 1024 = 64 batches x 4 seg x 4 parts
    const int b    = bx >> 4;
    const int seg  = (bx >> 2) & 3;
    const int part = bx & 3;
    const int s0   = seg * SEGLEN;

    // ---- stage this segment's increments into both LDS layouts ----
    const float* p = path + (size_t)b * (512 * CH) + s0 * CH;
    for (int e = tid; e < SEGLEN * CH; e += 256) {
        const int s = e / CH;
        const int c = e - s * CH;
        float v = 0.f;
        if (s0 + s < NSTEPS) v = p[e + CH] - p[e];   // seg 3 step 127 = 0 pad
        flatL[e] = v;
        trL[c * TRP + s] = v;
    }
    __syncthreads();

    const int id  = part * 256 + tid;     // chain id = i*100 + j*10 + k
    const int idc = (id < 1000) ? id : 999;   // tail lanes run a dummy chain
    const int ci = idc / 100;
    const int cj = (idc / 10) % 10;
    const int ck = idc % 10;

    float a1 = 0.f, a2 = 0.f, a3 = 0.f;
    float a4[10];
    #pragma unroll
    for (int l = 0; l < 10; ++l) a4[l] = 0.f;

    const float* ti = trL + ci * TRP;
    const float* tj = trL + cj * TRP;
    const float* tk = trL + ck * TRP;

    for (int g = 0; g < NGRP; ++g) {      // runtime loop (code size control)
        const float* fb = flatL + g * (GSTEPS * CH);
        // whole-wave row block: 320 floats -> 5 regs/lane, conflict-free
        const float f0 = fb[lane];
        const float f1 = fb[64 + lane];
        const float f2 = fb[128 + lane];
        const float f3 = fb[192 + lane];
        const float f4 = fb[256 + lane];
        const int gs = g * GSTEPS;

        #pragma unroll
        for (int q = 0; q < GSTEPS / 4; ++q) {
            const float4 vi = *(const float4*)(ti + gs + q * 4);
            const float4 vj = *(const float4*)(tj + gs + q * 4);
            const float4 vk = *(const float4*)(tk + gs + q * 4);
            #pragma unroll
            for (int u = 0; u < 4; ++u) {
                const int sl = q * 4 + u;            // 0..31 compile-time
                const float dxi = (u == 0) ? vi.x : (u == 1) ? vi.y
                                 : (u == 2) ? vi.z : vi.w;
                const float dxj = (u == 0) ? vj.x : (u == 1) ? vj.y
                                 : (u == 2) ? vj.z : vj.w;
                const float dxk = (u == 0) ? vk.x : (u == 1) ? vk.y
                                 : (u == 2) ? vk.z : vk.w;

                const float p1 = a1 * (1.f / 6.f) + dxi * (1.f / 24.f);
                const float q1 = a1 * 0.5f        + dxi * (1.f / 6.f);
                const float r1 = a1               + dxi * 0.5f;
                const float p2 = a2 * 0.5f + p1 * dxj;
                const float q2 = a2        + q1 * dxj;
                a2 += r1 * dxj;
                const float p3 = a3 + p2 * dxk;
                a3 += q2 * dxk;
                a1 += dxi;

                #pragma unroll
                for (int l = 0; l < 10; ++l) {
                    const int idx = sl * 10 + l;     // 0..319 compile-time
                    const float fs = ((idx >> 6) == 0) ? f0
                                   : ((idx >> 6) == 1) ? f1
                                   : ((idx >> 6) == 2) ? f2
                                   : ((idx >> 6) == 3) ? f3 : f4;
                    a4[l] += p3 * rl(fs, idx & 63);  // SGPR broadcast operand
                }
            }
        }
    }

    // ---- epilogue: write this chain's share of the segment partial ----
    if (id < 1000) {
        float* ob = ws + (size_t)(b * NSEG + seg) * WSSEG;
        float* o4 = ob + 1110 + id * 10;
        #pragma unroll
        for (int l = 0; l < 10; ++l) o4[l] = a4[l];
        ob[110 + id] = a3;
        if (ck == 0)            ob[10 + ci * 10 + cj] = a2;
        if (ck == 0 && cj == 0) ob[ci] = a1;
    }
}

__global__ __launch_bounds__(256)
void sig_combine(const float* __restrict__ ws, float* __restrict__ out) {
    __shared__ float B[1110];             // levels 1-3 of one segment partial

    const int tid  = threadIdx.x;
    const int b    = blockIdx.x >> 2;
    const int part = blockIdx.x & 3;
    const int id   = part * 256 + tid;
    const bool valid = (id < 1000);

    const int ci = id / 100;
    const int cj = (id / 10) % 10;
    const int ck = id % 10;

    const float* w0 = ws + (size_t)b * NSEG * WSSEG;

    float a1 = 0.f, a2 = 0.f, a3 = 0.f;
    float a4[10];
    #pragma unroll
    for (int l = 0; l < 10; ++l) a4[l] = 0.f;
    if (valid) {
        a1 = w0[ci];
        a2 = w0[10 + ci * 10 + cj];
        a3 = w0[110 + id];
        #pragma unroll
        for (int l = 0; l < 10; ++l) a4[l] = w0[1110 + id * 10 + l];
    }

    for (int s = 1; s < NSEG; ++s) {
        const float* wb = w0 + (size_t)s * WSSEG;
        __syncthreads();                  // previous iter done reading B
        for (int e = tid; e < 1110; e += 256) B[e] = wb[e];
        __syncthreads();

        if (valid) {
            const float b1i   = B[ci];
            const float b1j   = B[cj];
            const float b1k   = B[ck];
            const float b2_ij = B[10 + ci * 10 + cj];
            const float b2_jk = B[10 + cj * 10 + ck];
            const float b3ijk = B[110 + id];

            float b4v[10];
            #pragma unroll
            for (int l = 0; l < 10; ++l) b4v[l] = wb[1110 + id * 10 + l];

            // Z4 uses OLD a1,a2,a3 (computed before lower levels update)
            #pragma unroll
            for (int l = 0; l < 10; ++l)
                a4[l] += a3 * B[l] + a2 * B[10 + ck * 10 + l]
                       + a1 * B[110 + (cj * 10 + ck) * 10 + l] + b4v[l];
            a3 += a2 * b1k + a1 * b2_jk + b3ijk;
            a2 += a1 * b1j + b2_ij;
            a1 += b1i;
        }
    }

    if (valid) {
        float* ob = out + (size_t)b * SIGSZ;
        float* o4 = ob + 1110 + id * 10;
        #pragma unroll
        for (int l = 0; l < 10; ++l) o4[l] = a4[l];
        ob[110 + id] = a3;
        if (ck == 0)            ob[10 + ci * 10 + cj] = a2;
        if (ck == 0 && cj == 0) ob[ci] = a1;
    }
}

extern "C" void kernel_launch(void* const* d_in, const int* in_sizes, int n_in,
                              void* d_out, int out_size, void* d_ws, size_t ws_size,
                              hipStream_t stream) {
    const float* path = (const float*)d_in[0];   // [64, 512, 10] fp32
    float* out = (float*)d_out;                  // [64, 11110] fp32
    float* ws  = (float*)d_ws;                   // 64*4*11112 floats = 11.4 MB

    sig_partial<<<dim3(1024), dim3(256), 0, stream>>>(path, ws);
    sig_combine<<<dim3(256),  dim3(256), 0, stream>>>(ws, out);
}